// Round 5
// baseline (794.129 us; speedup 1.0000x reference)
//
#include <hip/hip_runtime.h>
#include <math.h>

#define NNODES 262144
#define HDIM   256
#define NHEADS 8
#define HEADD  32
#define NC     100
#define NLAYER 2
#define SPLIT  10
#define NBLK   (NNODES/256)   // 1024 hist/scatter blocks
#define KVPAD  36             // LDS row stride for 32-float head rows (kills bank conflicts)

__device__ __forceinline__ float gelu_exact(float v) {
    return 0.5f * v * (1.0f + erff(v * 0.70710678118654752440f));
}

__device__ __forceinline__ float dot4(float4 a, float4 b) {
    return a.x*b.x + a.y*b.y + a.z*b.z + a.w*b.w;
}

// sum across a 256-thread block; red must be __shared__ float[4]
__device__ __forceinline__ float blk_sum256(float v, float* red, int tid) {
    #pragma unroll
    for (int m = 32; m >= 1; m >>= 1) v += __shfl_xor(v, m, 64);
    if ((tid & 63) == 0) red[tid >> 6] = v;
    __syncthreads();
    float tot = red[0] + red[1] + red[2] + red[3];
    __syncthreads();
    return tot;
}

// ---------------- stage 0: qk_w[h][j] = sum_d q[h,d]*k_w[h*32+d][j] ----------------
__global__ void k_qkw(const float* __restrict__ q, const float* __restrict__ kw,
                      const float* __restrict__ kb, float* __restrict__ qk_w,
                      float* __restrict__ qk_b) {
    int h = blockIdx.x, j = threadIdx.x;
    float s = 0.f;
    #pragma unroll
    for (int d = 0; d < HEADD; ++d) s += q[h*HEADD + d] * kw[(h*HEADD + d)*HDIM + j];
    qk_w[h*HDIM + j] = s;
    if (j == 0) {
        float sb = 0.f;
        #pragma unroll
        for (int d = 0; d < HEADD; ++d) sb += q[h*HEADD + d] * kb[h*HEADD + d];
        qk_b[h] = sb;
    }
}

// ---------------- per-block histogram of commit indices ----------------
__global__ __launch_bounds__(256) void k_hist(const int* __restrict__ cidx,
                                              int* __restrict__ hist) {
    __shared__ int l_hist[NC];
    int tid = threadIdx.x;
    for (int i = tid; i < NC; i += 256) l_hist[i] = 0;
    __syncthreads();
    int c = cidx[blockIdx.x * 256 + tid];
    atomicAdd(&l_hist[c], 1);
    __syncthreads();
    for (int i = tid; i < NC; i += 256) hist[blockIdx.x*NC + i] = l_hist[i];
}

// ---------------- per-commit exclusive scan over block histograms ----------------
__global__ __launch_bounds__(256) void k_blockscan(const int* __restrict__ hist,
        int* __restrict__ bbase, int* __restrict__ counts) {
    int c = blockIdx.x, t = threadIdx.x;
    int v[4]; int loc = 0;
    #pragma unroll
    for (int i = 0; i < 4; ++i) { v[i] = hist[(t*4 + i)*NC + c]; loc += v[i]; }
    __shared__ int sc[256];
    sc[t] = loc; __syncthreads();
    for (int off = 1; off < 256; off <<= 1) {
        int x = (t >= off) ? sc[t - off] : 0;
        __syncthreads();
        sc[t] += x;
        __syncthreads();
    }
    int run = (t > 0) ? sc[t-1] : 0;
    #pragma unroll
    for (int i = 0; i < 4; ++i) { bbase[(t*4 + i)*NC + c] = run; run += v[i]; }
    if (t == 255) counts[c] = sc[255];
}

// ---------------- offs from counts (wave-parallel Hillis-Steele) ----------------
__global__ void k_scan(const int* __restrict__ counts, int* __restrict__ offs) {
    __shared__ int sc[128];
    int t = threadIdx.x;             // 128 threads
    int v = (t < NC) ? counts[t] : 0;
    sc[t] = v; __syncthreads();
    for (int off = 1; off < 128; off <<= 1) {
        int x = (t >= off) ? sc[t - off] : 0;
        __syncthreads();
        sc[t] += x;
        __syncthreads();
    }
    if (t <= NC) offs[t] = sc[t] - v;   // exclusive scan; offs[NC] = total
}

// ---------------- scatter into buckets (no global atomics) ----------------
__global__ __launch_bounds__(256) void k_scatter(const int* __restrict__ cidx,
        const int* __restrict__ offs, const int* __restrict__ bbase,
        int* __restrict__ nlist) {
    __shared__ int sb[NC];
    __shared__ int lcur[NC];
    int t = threadIdx.x, blk = blockIdx.x;
    if (t < NC) { sb[t] = offs[t] + bbase[blk*NC + t]; lcur[t] = 0; }
    __syncthreads();
    int n = blk * 256 + t;
    int c = cidx[n];
    int p = atomicAdd(&lcur[c], 1);
    nlist[sb[c] + p] = n;
}

// ---------------- FUSED gather + score + weighted accumulation (single emb pass) ----
// Per row: one 1KB row load; scores computed in-register (8x dot4, 17-shuffle
// transpose/butterfly, exp, 8 group-local broadcasts), then 32 FMA + den adds.
// 16-row chunks (16 nlist indices held per wave, broadcast from lane 4j) with a
// depth-6 named-register prefetch rotation: rows j..j+5 in flight, reissue at
// consume. Pipeline drains only every 16 rows. ~116 VGPR at (256,4).
__global__ __launch_bounds__(256, 4) void k_accum(const float* __restrict__ emb,
        const int* __restrict__ nlist, const int* __restrict__ offs,
        const int* __restrict__ counts, const float* __restrict__ qk_w,
        const float* __restrict__ qk_b, float* __restrict__ S_part,
        float* __restrict__ den_part) {
    int c  = blockIdx.x / SPLIT;
    int sl = blockIdx.x % SPLIT;
    int cnt = counts[c];
    __shared__ float s_buf[2][NHEADS*HDIM];   // 16 KB
    __shared__ float s_den[2][NHEADS];
    int tid = threadIdx.x, w = tid >> 6, lane = tid & 63;
    int s = lane & 7;
    int idx16 = lane >> 2;                    // 0..15: which chunk-row this lane's nn holds
    const float scale = 0.17677669529663688f;  // 32^-0.5

    float4 w4[NHEADS];
    #pragma unroll
    for (int h = 0; h < NHEADS; ++h)
        w4[h] = ((const float4*)(qk_w + h*HDIM))[lane];
    float qkb_s = qk_b[s];

    float4 acc[NHEADS];
    #pragma unroll
    for (int h = 0; h < NHEADS; ++h) acc[h] = make_float4(0.f, 0.f, 0.f, 0.f);
    float4 den_a = make_float4(0.f, 0.f, 0.f, 0.f);
    float4 den_b = make_float4(0.f, 0.f, 0.f, 0.f);

    int beg = offs[c];
    int per = (cnt + SPLIT - 1) / SPLIT;
    int s0 = min(cnt, sl * per), s1 = min(cnt, s0 + per);

#define ISSUE(j_, buf_) {                                                    \
    int nx_ = __shfl(nn, (j_)*4, 64);                                        \
    buf_ = ((const float4*)(emb + (size_t)nx_ * HDIM))[lane]; }

    int base = s0 + w*16;
    int nn = 0;
    if (base < s1) {
        int nb0 = min(16, s1 - base);
        if (idx16 < nb0) nn = nlist[beg + base + idx16];
    }
    for (; base < s1; base += 64) {
        int nb = min(16, s1 - base);
        // prefetch next chunk's nlist early
        int nn_next = 0;
        int base2 = base + 64;
        if (base2 < s1) {
            int nb2 = min(16, s1 - base2);
            if (idx16 < nb2) nn_next = nlist[beg + base2 + idx16];
        }
        float4 e0, e1, e2, e3, e4, e5;
        ISSUE(0, e0);
        if (1 < nb) ISSUE(1, e1);
        if (2 < nb) ISSUE(2, e2);
        if (3 < nb) ISSUE(3, e3);
        if (4 < nb) ISSUE(4, e4);
        if (5 < nb) ISSUE(5, e5);
        #pragma unroll
        for (int i2 = 0; i2 < 16; ++i2) {
            if (i2 >= nb) break;
            // grab current row, immediately reissue its buffer with row i2+6
            float4 e_c;
            switch (i2 % 6) {
            case 0: e_c = e0; if (i2 + 6 < nb) ISSUE(i2 + 6, e0) break;
            case 1: e_c = e1; if (i2 + 6 < nb) ISSUE(i2 + 6, e1) break;
            case 2: e_c = e2; if (i2 + 6 < nb) ISSUE(i2 + 6, e2) break;
            case 3: e_c = e3; if (i2 + 6 < nb) ISSUE(i2 + 6, e3) break;
            case 4: e_c = e4; if (i2 + 6 < nb) ISSUE(i2 + 6, e4) break;
            default: e_c = e5; if (i2 + 6 < nb) ISSUE(i2 + 6, e5) break;
            }
            // ---- in-register score: p[h] -> transpose-reduce -> exp ----
            float p[NHEADS];
            #pragma unroll
            for (int h = 0; h < NHEADS; ++h) p[h] = dot4(e_c, w4[h]);
            float q0, q1, q2, q3;
            {
                bool sel = (s & 1) != 0;
                float a0 = __shfl_xor(p[0], 1, 64), a1 = __shfl_xor(p[1], 1, 64);
                q0 = sel ? (p[1] + a1) : (p[0] + a0);
                float a2 = __shfl_xor(p[2], 1, 64), a3 = __shfl_xor(p[3], 1, 64);
                q1 = sel ? (p[3] + a3) : (p[2] + a2);
                float a4 = __shfl_xor(p[4], 1, 64), a5 = __shfl_xor(p[5], 1, 64);
                q2 = sel ? (p[5] + a5) : (p[4] + a4);
                float a6 = __shfl_xor(p[6], 1, 64), a7 = __shfl_xor(p[7], 1, 64);
                q3 = sel ? (p[7] + a7) : (p[6] + a6);
            }
            float r0v, r1v;
            {
                bool sel = (s & 2) != 0;
                float b0 = __shfl_xor(q0, 2, 64), b1 = __shfl_xor(q1, 2, 64);
                r0v = sel ? (q1 + b1) : (q0 + b0);
                float b2 = __shfl_xor(q2, 2, 64), b3 = __shfl_xor(q3, 2, 64);
                r1v = sel ? (q3 + b3) : (q2 + b2);
            }
            float tt;
            {
                bool sel = (s & 4) != 0;
                float c0 = __shfl_xor(r0v, 4, 64), c1 = __shfl_xor(r1v, 4, 64);
                tt = sel ? (r1v + c1) : (r0v + c0);
            }
            tt += __shfl_xor(tt, 8, 64);
            tt += __shfl_xor(tt, 16, 64);
            tt += __shfl_xor(tt, 32, 64);
            float evv = __expf((tt + qkb_s) * scale);
            // broadcast all 8 head evs into each lane (group-local, width 8)
            float4 va, vb;
            va.x = __shfl(evv, 0, 8); va.y = __shfl(evv, 1, 8);
            va.z = __shfl(evv, 2, 8); va.w = __shfl(evv, 3, 8);
            vb.x = __shfl(evv, 4, 8); vb.y = __shfl(evv, 5, 8);
            vb.z = __shfl(evv, 6, 8); vb.w = __shfl(evv, 7, 8);
            den_a.x += va.x; den_a.y += va.y; den_a.z += va.z; den_a.w += va.w;
            den_b.x += vb.x; den_b.y += vb.y; den_b.z += vb.z; den_b.w += vb.w;
            acc[0].x += va.x * e_c.x; acc[0].y += va.x * e_c.y;
            acc[0].z += va.x * e_c.z; acc[0].w += va.x * e_c.w;
            acc[1].x += va.y * e_c.x; acc[1].y += va.y * e_c.y;
            acc[1].z += va.y * e_c.z; acc[1].w += va.y * e_c.w;
            acc[2].x += va.z * e_c.x; acc[2].y += va.z * e_c.y;
            acc[2].z += va.z * e_c.z; acc[2].w += va.z * e_c.w;
            acc[3].x += va.w * e_c.x; acc[3].y += va.w * e_c.y;
            acc[3].z += va.w * e_c.z; acc[3].w += va.w * e_c.w;
            acc[4].x += vb.x * e_c.x; acc[4].y += vb.x * e_c.y;
            acc[4].z += vb.x * e_c.z; acc[4].w += vb.x * e_c.w;
            acc[5].x += vb.y * e_c.x; acc[5].y += vb.y * e_c.y;
            acc[5].z += vb.y * e_c.z; acc[5].w += vb.y * e_c.w;
            acc[6].x += vb.z * e_c.x; acc[6].y += vb.z * e_c.y;
            acc[6].z += vb.z * e_c.z; acc[6].w += vb.z * e_c.w;
            acc[7].x += vb.w * e_c.x; acc[7].y += vb.w * e_c.y;
            acc[7].z += vb.w * e_c.z; acc[7].w += vb.w * e_c.w;
        }
        nn = nn_next;
    }
#undef ISSUE

    // ---- 2-stage cross-wave tree reduction ----
    if (w >= 2) {
        #pragma unroll
        for (int h2 = 0; h2 < NHEADS; ++h2)
            ((float4*)&s_buf[w-2][h2*HDIM])[lane] = acc[h2];
        if (lane == 0) {
            s_den[w-2][0] = den_a.x; s_den[w-2][1] = den_a.y;
            s_den[w-2][2] = den_a.z; s_den[w-2][3] = den_a.w;
            s_den[w-2][4] = den_b.x; s_den[w-2][5] = den_b.y;
            s_den[w-2][6] = den_b.z; s_den[w-2][7] = den_b.w;
        }
    }
    __syncthreads();
    if (w < 2) {
        #pragma unroll
        for (int h2 = 0; h2 < NHEADS; ++h2) {
            float4 v = ((const float4*)&s_buf[w][h2*HDIM])[lane];
            acc[h2].x += v.x; acc[h2].y += v.y; acc[h2].z += v.z; acc[h2].w += v.w;
        }
        den_a.x += s_den[w][0]; den_a.y += s_den[w][1];
        den_a.z += s_den[w][2]; den_a.w += s_den[w][3];
        den_b.x += s_den[w][4]; den_b.y += s_den[w][5];
        den_b.z += s_den[w][6]; den_b.w += s_den[w][7];
    }
    __syncthreads();
    if (w == 1) {
        #pragma unroll
        for (int h2 = 0; h2 < NHEADS; ++h2)
            ((float4*)&s_buf[0][h2*HDIM])[lane] = acc[h2];
        if (lane == 0) {
            s_den[0][0] = den_a.x; s_den[0][1] = den_a.y;
            s_den[0][2] = den_a.z; s_den[0][3] = den_a.w;
            s_den[0][4] = den_b.x; s_den[0][5] = den_b.y;
            s_den[0][6] = den_b.z; s_den[0][7] = den_b.w;
        }
    }
    __syncthreads();
    if (w == 0) {
        float* Sd = S_part + ((size_t)sl*NC + c) * (NHEADS*HDIM);
        #pragma unroll
        for (int h2 = 0; h2 < NHEADS; ++h2) {
            float4 v = ((const float4*)&s_buf[0][h2*HDIM])[lane];
            v.x += acc[h2].x; v.y += acc[h2].y; v.z += acc[h2].z; v.w += acc[h2].w;
            ((float4*)(Sd + h2*HDIM))[lane] = v;
        }
        if (lane == 0) {
            float* dp = den_part + ((size_t)sl*NC + c) * NHEADS;
            dp[0] = den_a.x + s_den[0][0]; dp[1] = den_a.y + s_den[0][1];
            dp[2] = den_a.z + s_den[0][2]; dp[3] = den_a.w + s_den[0][3];
            dp[4] = den_b.x + s_den[0][4]; dp[5] = den_b.y + s_den[0][5];
            dp[6] = den_b.z + s_den[0][6]; dp[7] = den_b.w + s_den[0][7];
        }
    }
}

// ---------------- stage 3: pooled -> po proj -> LN -> x ----------------
__global__ __launch_bounds__(256) void k_pool(const float* __restrict__ S_part,
        const float* __restrict__ den_part, const int* __restrict__ counts,
        const float* __restrict__ vw, const float* __restrict__ vb,
        const float* __restrict__ pow_, const float* __restrict__ pob,
        const float* __restrict__ png, const float* __restrict__ pnb,
        float* __restrict__ x) {
    int c = blockIdx.x, t = threadIdx.x;
    __shared__ float S_l[NHEADS*HDIM];  // 2048 floats
    __shared__ float pooled[HDIM];
    __shared__ float red[4];
    {
        float4 a0 = make_float4(0.f,0.f,0.f,0.f), a1 = a0;
        #pragma unroll
        for (int sl = 0; sl < SPLIT; ++sl) {
            const float4* sp = (const float4*)(S_part + ((size_t)sl*NC + c) * (NHEADS*HDIM));
            float4 v0 = sp[t], v1 = sp[t + 256];
            a0.x += v0.x; a0.y += v0.y; a0.z += v0.z; a0.w += v0.w;
            a1.x += v1.x; a1.y += v1.y; a1.z += v1.z; a1.w += v1.w;
        }
        ((float4*)S_l)[t] = a0;
        ((float4*)S_l)[t + 256] = a1;
    }
    int h = t >> 5;
    float dh = 0.f;
    #pragma unroll
    for (int sl = 0; sl < SPLIT; ++sl) dh += den_part[(sl*NC + c)*NHEADS + h];
    __syncthreads();
    float dx = dh > 0.f ? dh : 1.f;
    float s = vb[t] * dh;
    const float4* wr = (const float4*)(vw + (size_t)t * HDIM);
    const float4* sr = (const float4*)(S_l + h * HDIM);
    #pragma unroll 8
    for (int j = 0; j < HDIM/4; ++j) s += dot4(wr[j], sr[j]);
    pooled[t] = s / dx;
    __syncthreads();
    float o = pob[t];
    const float4* pr = (const float4*)(pow_ + (size_t)t * HDIM);
    const float4* pv = (const float4*)pooled;
    #pragma unroll 8
    for (int j = 0; j < HDIM/4; ++j) o += dot4(pr[j], pv[j]);
    float mu  = blk_sum256(o, red, t) * (1.f/256.f);
    float d   = o - mu;
    float var = blk_sum256(d*d, red, t) * (1.f/256.f);
    float y = d * rsqrtf(var + 1e-5f) * png[t] + pnb[t];
    x[c*HDIM + t] = (counts[c] > 0) ? y : 0.f;
}

// ---------------- generic small matmul: out[r][p] = in[r,:] . W[p,:] + b (opt gelu) ----------------
__global__ __launch_bounds__(256) void k_mm(const float* __restrict__ in,
        const float* __restrict__ W, const float* __restrict__ bias,
        float* __restrict__ out, int K, int P, int do_gelu) {
    int r = blockIdx.x;
    int p = blockIdx.y * 256 + threadIdx.x;
    __shared__ float xr[1024];
    for (int idx = threadIdx.x; idx < K; idx += 256) xr[idx] = in[(size_t)r*K + idx];
    __syncthreads();
    float s = bias[p];
    const float4* wr = (const float4*)(W + (size_t)p * K);
    const float4* xv = (const float4*)xr;
    for (int j = 0; j < (K >> 2); ++j) s += dot4(wr[j], xv[j]);
    if (do_gelu) s = gelu_exact(s);
    out[(size_t)r*P + p] = s;
}

// ---------------- matmul + residual + layernorm (writes x in place) ----------------
__global__ __launch_bounds__(256) void k_mm_res_ln(const float* __restrict__ in,
        const float* __restrict__ W, const float* __restrict__ bias,
        const float* __restrict__ g, const float* __restrict__ be,
        float* __restrict__ x, int K) {
    int r = blockIdx.x, t = threadIdx.x;
    __shared__ float xr[1024];
    __shared__ float red[4];
    for (int idx = t; idx < K; idx += 256) xr[idx] = in[(size_t)r*K + idx];
    __syncthreads();
    float s = bias[t];
    const float4* wr = (const float4*)(W + (size_t)t * K);
    const float4* xv = (const float4*)xr;
    for (int j = 0; j < (K >> 2); ++j) s += dot4(wr[j], xv[j]);
    float v = x[r*HDIM + t] + s;
    float mu  = blk_sum256(v, red, t) * (1.f/256.f);
    float d   = v - mu;
    float var = blk_sum256(d*d, red, t) * (1.f/256.f);
    x[r*HDIM + t] = d * rsqrtf(var + 1e-5f) * g[t] + be[t];
}

// ---------------- per-head attention over C=100, row-split 4x ----------------
// grid (NHEADS, 4): block handles rows [ns*25, ns*25+25) for head h.
// K,V,Q staged in LDS at stride KVPAD=36 floats (16B-aligned, spreads the
// stride-128B b128 reads across bank-quads); softmax in 8-lane groups; AV
// entirely from LDS (was ~100 scattered 4B global reads per output).
__global__ __launch_bounds__(256) void k_attn(const float* __restrict__ qkv,
        float* __restrict__ attn_out) {
    int h = blockIdx.x, ns = blockIdx.y, t = threadIdx.x;
    int n0 = ns * 25;
    __shared__ float k_l[NC * KVPAD];     // 14.4 KB
    __shared__ float v_l[NC * KVPAD];     // 14.4 KB
    __shared__ float q_l[25 * KVPAD];     // 3.6 KB
    __shared__ float sc[25 * NC];         // 10 KB
    for (int idx = t; idx < NC*HEADD; idx += 256) {
        int n = idx >> 5, d = idx & 31;
        k_l[n*KVPAD + d] = qkv[n*768 + 256 + h*HEADD + d];
        v_l[n*KVPAD + d] = qkv[n*768 + 512 + h*HEADD + d];
    }
    for (int idx = t; idx < 25*HEADD; idx += 256) {
        int n = idx >> 5, d = idx & 31;
        q_l[n*KVPAD + d] = qkv[(n0 + n)*768 + h*HEADD + d];
    }
    __syncthreads();
    const float scale = 0.17677669529663688f;
    for (int idx = t; idx < 25*NC; idx += 256) {
        int n = idx / NC, m = idx - n*NC;
        const float4* q4 = (const float4*)(q_l + n*KVPAD);
        const float4* k4 = (const float4*)(k_l + m*KVPAD);
        float s = 0.f;
        #pragma unroll
        for (int j = 0; j < HEADD/4; ++j) s += dot4(q4[j], k4[j]);
        sc[idx] = s * scale;
    }
    __syncthreads();
    {   // softmax: one 8-lane group per row
        int g = t >> 3, gl = t & 7;
        if (g < 25) {
            float mx = -1e30f;
            for (int m = gl; m < NC; m += 8) mx = fmaxf(mx, sc[g*NC + m]);
            #pragma unroll
            for (int o = 4; o >= 1; o >>= 1) mx = fmaxf(mx, __shfl_xor(mx, o, 8));
            float sum = 0.f;
            for (int m = gl; m < NC; m += 8) {
                float e = expf(sc[g*NC + m] - mx);
                sc[g*NC + m] = e; sum += e;
            }
            #pragma unroll
            for (int o = 4; o >= 1; o >>= 1) sum += __shfl_xor(sum, o, 8);
            float inv = 1.f / sum;
            for (int m = gl; m < NC; m += 8) sc[g*NC + m] *= inv;
        }
    }
    __syncthreads();
    for (int idx = t; idx < 25*HEADD; idx += 256) {
        int n = idx >> 5, d = idx & 31;
        float o = 0.f;
        #pragma unroll 4
        for (int m = 0; m < NC; ++m) o += sc[n*NC + m] * v_l[m*KVPAD + d];
        attn_out[(n0 + n)*HDIM + h*HEADD + d] = o;
    }
}

// ---------------- ranking head ----------------
__global__ __launch_bounds__(128) void k_head(const float* __restrict__ x,
        const float* __restrict__ r1w, const float* __restrict__ r1b,
        const float* __restrict__ r2w, const float* __restrict__ r2b,
        float* __restrict__ out) {
    int r = blockIdx.x, t = threadIdx.x;
    __shared__ float xr[HDIM];
    __shared__ float red[2];
    xr[t] = x[r*HDIM + t];
    xr[t + 128] = x[r*HDIM + t + 128];
    __syncthreads();
    float s = r1b[t];
    const float4* wr = (const float4*)(r1w + (size_t)t * HDIM);
    const float4* xv = (const float4*)xr;
    #pragma unroll 8
    for (int j = 0; j < HDIM/4; ++j) s += dot4(wr[j], xv[j]);
    s = gelu_exact(s);
    float contrib = s * r2w[t];
    #pragma unroll
    for (int m = 32; m >= 1; m >>= 1) contrib += __shfl_xor(contrib, m, 64);
    if ((t & 63) == 0) red[t >> 6] = contrib;
    __syncthreads();
    if (t == 0) out[r] = red[0] + red[1] + r2b[0];
}

extern "C" void kernel_launch(void* const* d_in, const int* in_sizes, int n_in,
                              void* d_out, int out_size, void* d_ws, size_t ws_size,
                              hipStream_t stream) {
    const float* emb   = (const float*)d_in[0];
    const int*   cidx  = (const int*)d_in[1];
    const float* q     = (const float*)d_in[3];
    const float* kw    = (const float*)d_in[4];
    const float* kb    = (const float*)d_in[5];
    const float* vw    = (const float*)d_in[6];
    const float* vb    = (const float*)d_in[7];
    const float* pow_  = (const float*)d_in[8];
    const float* pob   = (const float*)d_in[9];
    const float* png   = (const float*)d_in[10];
    const float* pnb   = (const float*)d_in[11];
    const float* tinw  = (const float*)d_in[12];
    const float* tinb  = (const float*)d_in[13];
    const float* toutw = (const float*)d_in[14];
    const float* toutb = (const float*)d_in[15];
    const float* ln1g  = (const float*)d_in[16];
    const float* ln1b  = (const float*)d_in[17];
    const float* ff1w  = (const float*)d_in[18];
    const float* ff1b  = (const float*)d_in[19];
    const float* ff2w  = (const float*)d_in[20];
    const float* ff2b  = (const float*)d_in[21];
    const float* ln2g  = (const float*)d_in[22];
    const float* ln2b  = (const float*)d_in[23];
    const float* r1w   = (const float*)d_in[24];
    const float* r1b   = (const float*)d_in[25];
    const float* r2w   = (const float*)d_in[26];
    const float* r2b   = (const float*)d_in[27];
    float* out = (float*)d_out;

    // --- workspace bump allocator (256B aligned) ---
    char* ws = (char*)d_ws;
    size_t off = 0;
    auto alloc = [&](size_t bytes) -> char* {
        off = (off + 255) & ~(size_t)255;
        char* p = ws + off;
        off += bytes;
        return p;
    };
    int*   hist   = (int*)alloc((size_t)NBLK * NC * 4);                          // 0.41 MB
    int*   bbase  = (int*)alloc((size_t)NBLK * NC * 4);                          // 0.41 MB
    int*   counts = (int*)alloc(NC * 4);
    int*   offs   = (int*)alloc((NC + 1) * 4);
    float* den_p  = (float*)alloc((size_t)SPLIT * NC * NHEADS * 4);
    float* S_part = (float*)alloc((size_t)SPLIT * NC * NHEADS * HDIM * 4);       // 8.2 MB
    float* qk_w   = (float*)alloc(NHEADS * HDIM * 4);
    float* qk_b   = (float*)alloc(NHEADS * 4);
    int*   nlist  = (int*)alloc((size_t)NNODES * 4);                             // 1 MB
    float* x      = (float*)alloc(NC * HDIM * 4);
    float* qkv    = (float*)alloc(NC * 3 * HDIM * 4);
    float* attn_o = (float*)alloc(NC * HDIM * 4);
    float* ffb    = (float*)alloc(NC * 4 * HDIM * 4);
    (void)ws_size; (void)in_sizes; (void)n_in; (void)out_size;

    k_qkw<<<NHEADS, HDIM, 0, stream>>>(q, kw, kb, qk_w, qk_b);
    k_hist<<<NBLK, 256, 0, stream>>>(cidx, hist);
    k_blockscan<<<NC, 256, 0, stream>>>(hist, bbase, counts);
    k_scan<<<1, 128, 0, stream>>>(counts, offs);
    k_scatter<<<NBLK, 256, 0, stream>>>(cidx, offs, bbase, nlist);
    k_accum<<<NC*SPLIT, 256, 0, stream>>>(emb, nlist, offs, counts, qk_w, qk_b, S_part, den_p);
    k_pool<<<NC, 256, 0, stream>>>(S_part, den_p, counts, vw, vb, pow_, pob, png, pnb, x);

    for (int l = 0; l < NLAYER; ++l) {
        k_mm<<<dim3(NC, 3), 256, 0, stream>>>(x, tinw + (size_t)l*3*HDIM*HDIM,
                                              tinb + (size_t)l*3*HDIM, qkv, HDIM, 3*HDIM, 0);
        k_attn<<<dim3(NHEADS, 4), 256, 0, stream>>>(qkv, attn_o);
        k_mm_res_ln<<<NC, 256, 0, stream>>>(attn_o, toutw + (size_t)l*HDIM*HDIM,
                                            toutb + (size_t)l*HDIM, ln1g + (size_t)l*HDIM,
                                            ln1b + (size_t)l*HDIM, x, HDIM);
        k_mm<<<dim3(NC, 4), 256, 0, stream>>>(x, ff1w + (size_t)l*4*HDIM*HDIM,
                                              ff1b + (size_t)l*4*HDIM, ffb, HDIM, 4*HDIM, 1);
        k_mm_res_ln<<<NC, 256, 0, stream>>>(ffb, ff2w + (size_t)l*HDIM*4*HDIM,
                                            ff2b + (size_t)l*HDIM, ln2g + (size_t)l*HDIM,
                                            ln2b + (size_t)l*HDIM, x, 4*HDIM);
    }
    k_head<<<NC, 128, 0, stream>>>(x, r1w, r1b, r2w, r2b, out);
}

// Round 6
// 663.328 us; speedup vs baseline: 1.1972x; 1.1972x over previous
//
#include <hip/hip_runtime.h>
#include <math.h>

#define NNODES 262144
#define HDIM   256
#define NHEADS 8
#define HEADD  32
#define NC     100
#define NLAYER 2
#define SPLIT  10
#define NBLK   (NNODES/256)   // 1024 hist/scatter blocks
#define KVPAD  36             // LDS row stride for 32-float head rows (kills bank conflicts)

__device__ __forceinline__ float gelu_exact(float v) {
    return 0.5f * v * (1.0f + erff(v * 0.70710678118654752440f));
}

__device__ __forceinline__ float dot4(float4 a, float4 b) {
    return a.x*b.x + a.y*b.y + a.z*b.z + a.w*b.w;
}

// sum across a 256-thread block; red must be __shared__ float[4]
__device__ __forceinline__ float blk_sum256(float v, float* red, int tid) {
    #pragma unroll
    for (int m = 32; m >= 1; m >>= 1) v += __shfl_xor(v, m, 64);
    if ((tid & 63) == 0) red[tid >> 6] = v;
    __syncthreads();
    float tot = red[0] + red[1] + red[2] + red[3];
    __syncthreads();
    return tot;
}

// ---------------- stage 0: qk_w[h][j] = sum_d q[h,d]*k_w[h*32+d][j] ----------------
__global__ void k_qkw(const float* __restrict__ q, const float* __restrict__ kw,
                      const float* __restrict__ kb, float* __restrict__ qk_w,
                      float* __restrict__ qk_b) {
    int h = blockIdx.x, j = threadIdx.x;
    float s = 0.f;
    #pragma unroll
    for (int d = 0; d < HEADD; ++d) s += q[h*HEADD + d] * kw[(h*HEADD + d)*HDIM + j];
    qk_w[h*HDIM + j] = s;
    if (j == 0) {
        float sb = 0.f;
        #pragma unroll
        for (int d = 0; d < HEADD; ++d) sb += q[h*HEADD + d] * kb[h*HEADD + d];
        qk_b[h] = sb;
    }
}

// ---------------- per-block histogram of commit indices ----------------
__global__ __launch_bounds__(256) void k_hist(const int* __restrict__ cidx,
                                              int* __restrict__ hist) {
    __shared__ int l_hist[NC];
    int tid = threadIdx.x;
    for (int i = tid; i < NC; i += 256) l_hist[i] = 0;
    __syncthreads();
    int c = cidx[blockIdx.x * 256 + tid];
    atomicAdd(&l_hist[c], 1);
    __syncthreads();
    for (int i = tid; i < NC; i += 256) hist[blockIdx.x*NC + i] = l_hist[i];
}

// ---------------- per-commit exclusive scan over block histograms ----------------
__global__ __launch_bounds__(256) void k_blockscan(const int* __restrict__ hist,
        int* __restrict__ bbase, int* __restrict__ counts) {
    int c = blockIdx.x, t = threadIdx.x;
    int v[4]; int loc = 0;
    #pragma unroll
    for (int i = 0; i < 4; ++i) { v[i] = hist[(t*4 + i)*NC + c]; loc += v[i]; }
    __shared__ int sc[256];
    sc[t] = loc; __syncthreads();
    for (int off = 1; off < 256; off <<= 1) {
        int x = (t >= off) ? sc[t - off] : 0;
        __syncthreads();
        sc[t] += x;
        __syncthreads();
    }
    int run = (t > 0) ? sc[t-1] : 0;
    #pragma unroll
    for (int i = 0; i < 4; ++i) { bbase[(t*4 + i)*NC + c] = run; run += v[i]; }
    if (t == 255) counts[c] = sc[255];
}

// ---------------- offs from counts (wave-parallel Hillis-Steele) ----------------
__global__ void k_scan(const int* __restrict__ counts, int* __restrict__ offs) {
    __shared__ int sc[128];
    int t = threadIdx.x;             // 128 threads
    int v = (t < NC) ? counts[t] : 0;
    sc[t] = v; __syncthreads();
    for (int off = 1; off < 128; off <<= 1) {
        int x = (t >= off) ? sc[t - off] : 0;
        __syncthreads();
        sc[t] += x;
        __syncthreads();
    }
    if (t <= NC) offs[t] = sc[t] - v;   // exclusive scan; offs[NC] = total
}

// ---------------- scatter into buckets (no global atomics) ----------------
__global__ __launch_bounds__(256) void k_scatter(const int* __restrict__ cidx,
        const int* __restrict__ offs, const int* __restrict__ bbase,
        int* __restrict__ nlist) {
    __shared__ int sb[NC];
    __shared__ int lcur[NC];
    int t = threadIdx.x, blk = blockIdx.x;
    if (t < NC) { sb[t] = offs[t] + bbase[blk*NC + t]; lcur[t] = 0; }
    __syncthreads();
    int n = blk * 256 + t;
    int c = cidx[n];
    int p = atomicAdd(&lcur[c], 1);
    nlist[sb[c] + p] = n;
}

// ---------------- FUSED gather + score + weighted accumulation (single emb pass) ----
// Per row: one 1KB row load; scores computed in-register (8x dot4, 17-shuffle
// transpose/butterfly, exp, 8 group-local broadcasts), then 32 FMA + den adds.
// Depth-4 named-register prefetch rotation with if/else (NOT switch: R5's
// switch(i2%6) rotation collapsed VGPRs to 64 and serialized the pipeline —
// verify VGPR_Count ~116 after any edit here). 8-row chunks, reissue at i2+4.
// ~112 VGPR -> __launch_bounds__(256,4), SPLIT=10 -> 1000 blocks, 4 blk/CU.
__global__ __launch_bounds__(256, 4) void k_accum(const float* __restrict__ emb,
        const int* __restrict__ nlist, const int* __restrict__ offs,
        const int* __restrict__ counts, const float* __restrict__ qk_w,
        const float* __restrict__ qk_b, float* __restrict__ S_part,
        float* __restrict__ den_part) {
    int c  = blockIdx.x / SPLIT;
    int sl = blockIdx.x % SPLIT;
    int cnt = counts[c];
    __shared__ float s_buf[2][NHEADS*HDIM];   // 16 KB
    __shared__ float s_den[2][NHEADS];
    int tid = threadIdx.x, w = tid >> 6, lane = tid & 63;
    int s = lane & 7, i = lane >> 3;
    const float scale = 0.17677669529663688f;  // 32^-0.5

    float4 w4[NHEADS];
    #pragma unroll
    for (int h = 0; h < NHEADS; ++h)
        w4[h] = ((const float4*)(qk_w + h*HDIM))[lane];
    float qkb_s = qk_b[s];

    float4 acc[NHEADS];
    #pragma unroll
    for (int h = 0; h < NHEADS; ++h) acc[h] = make_float4(0.f, 0.f, 0.f, 0.f);
    float4 den_a = make_float4(0.f, 0.f, 0.f, 0.f);
    float4 den_b = make_float4(0.f, 0.f, 0.f, 0.f);

    int beg = offs[c];
    int per = (cnt + SPLIT - 1) / SPLIT;
    int s0 = min(cnt, sl * per), s1 = min(cnt, s0 + per);

#define ISSUE(j_, buf_) {                                                    \
    int nx_ = __shfl(nn, (j_)*8, 64);                                        \
    buf_ = ((const float4*)(emb + (size_t)nx_ * HDIM))[lane]; }

    int base = s0 + w*8;
    int nn = 0;
    if (base < s1) {
        int nb0 = min(8, s1 - base);
        if (i < nb0) nn = nlist[beg + base + i];
    }
    for (; base < s1; base += 32) {
        int nb = min(8, s1 - base);
        // prefetch next chunk's nlist early
        int nn_next = 0;
        int base2 = base + 32;
        if (base2 < s1) {
            int nb2 = min(8, s1 - base2);
            if (i < nb2) nn_next = nlist[beg + base2 + i];
        }
        float4 e0, e1, e2, e3;
        ISSUE(0, e0);
        if (1 < nb) ISSUE(1, e1);
        if (2 < nb) ISSUE(2, e2);
        if (3 < nb) ISSUE(3, e3);
        #pragma unroll
        for (int i2 = 0; i2 < 8; ++i2) {
            if (i2 >= nb) break;
            // grab current row, immediately reissue its buffer with row i2+4
            float4 e_c;
            if      ((i2 & 3) == 0) { e_c = e0; if (i2 + 4 < nb) ISSUE(i2 + 4, e0) }
            else if ((i2 & 3) == 1) { e_c = e1; if (i2 + 4 < nb) ISSUE(i2 + 4, e1) }
            else if ((i2 & 3) == 2) { e_c = e2; if (i2 + 4 < nb) ISSUE(i2 + 4, e2) }
            else                    { e_c = e3; if (i2 + 4 < nb) ISSUE(i2 + 4, e3) }
            // ---- in-register score: p[h] -> transpose-reduce -> exp ----
            float p[NHEADS];
            #pragma unroll
            for (int h = 0; h < NHEADS; ++h) p[h] = dot4(e_c, w4[h]);
            float q0, q1, q2, q3;
            {
                bool sel = (s & 1) != 0;
                float a0 = __shfl_xor(p[0], 1, 64), a1 = __shfl_xor(p[1], 1, 64);
                q0 = sel ? (p[1] + a1) : (p[0] + a0);
                float a2 = __shfl_xor(p[2], 1, 64), a3 = __shfl_xor(p[3], 1, 64);
                q1 = sel ? (p[3] + a3) : (p[2] + a2);
                float a4 = __shfl_xor(p[4], 1, 64), a5 = __shfl_xor(p[5], 1, 64);
                q2 = sel ? (p[5] + a5) : (p[4] + a4);
                float a6 = __shfl_xor(p[6], 1, 64), a7 = __shfl_xor(p[7], 1, 64);
                q3 = sel ? (p[7] + a7) : (p[6] + a6);
            }
            float r0v, r1v;
            {
                bool sel = (s & 2) != 0;
                float b0 = __shfl_xor(q0, 2, 64), b1 = __shfl_xor(q1, 2, 64);
                r0v = sel ? (q1 + b1) : (q0 + b0);
                float b2 = __shfl_xor(q2, 2, 64), b3 = __shfl_xor(q3, 2, 64);
                r1v = sel ? (q3 + b3) : (q2 + b2);
            }
            float tt;
            {
                bool sel = (s & 4) != 0;
                float c0 = __shfl_xor(r0v, 4, 64), c1 = __shfl_xor(r1v, 4, 64);
                tt = sel ? (r1v + c1) : (r0v + c0);
            }
            tt += __shfl_xor(tt, 8, 64);
            tt += __shfl_xor(tt, 16, 64);
            tt += __shfl_xor(tt, 32, 64);
            float evv = __expf((tt + qkb_s) * scale);
            // broadcast all 8 head evs into each lane (group-local, width 8)
            float4 va, vb;
            va.x = __shfl(evv, 0, 8); va.y = __shfl(evv, 1, 8);
            va.z = __shfl(evv, 2, 8); va.w = __shfl(evv, 3, 8);
            vb.x = __shfl(evv, 4, 8); vb.y = __shfl(evv, 5, 8);
            vb.z = __shfl(evv, 6, 8); vb.w = __shfl(evv, 7, 8);
            den_a.x += va.x; den_a.y += va.y; den_a.z += va.z; den_a.w += va.w;
            den_b.x += vb.x; den_b.y += vb.y; den_b.z += vb.z; den_b.w += vb.w;
            acc[0].x += va.x * e_c.x; acc[0].y += va.x * e_c.y;
            acc[0].z += va.x * e_c.z; acc[0].w += va.x * e_c.w;
            acc[1].x += va.y * e_c.x; acc[1].y += va.y * e_c.y;
            acc[1].z += va.y * e_c.z; acc[1].w += va.y * e_c.w;
            acc[2].x += va.z * e_c.x; acc[2].y += va.z * e_c.y;
            acc[2].z += va.z * e_c.z; acc[2].w += va.z * e_c.w;
            acc[3].x += va.w * e_c.x; acc[3].y += va.w * e_c.y;
            acc[3].z += va.w * e_c.z; acc[3].w += va.w * e_c.w;
            acc[4].x += vb.x * e_c.x; acc[4].y += vb.x * e_c.y;
            acc[4].z += vb.x * e_c.z; acc[4].w += vb.x * e_c.w;
            acc[5].x += vb.y * e_c.x; acc[5].y += vb.y * e_c.y;
            acc[5].z += vb.y * e_c.z; acc[5].w += vb.y * e_c.w;
            acc[6].x += vb.z * e_c.x; acc[6].y += vb.z * e_c.y;
            acc[6].z += vb.z * e_c.z; acc[6].w += vb.z * e_c.w;
            acc[7].x += vb.w * e_c.x; acc[7].y += vb.w * e_c.y;
            acc[7].z += vb.w * e_c.z; acc[7].w += vb.w * e_c.w;
        }
        nn = nn_next;
    }
#undef ISSUE

    // ---- 2-stage cross-wave tree reduction ----
    if (w >= 2) {
        #pragma unroll
        for (int h2 = 0; h2 < NHEADS; ++h2)
            ((float4*)&s_buf[w-2][h2*HDIM])[lane] = acc[h2];
        if (lane == 0) {
            s_den[w-2][0] = den_a.x; s_den[w-2][1] = den_a.y;
            s_den[w-2][2] = den_a.z; s_den[w-2][3] = den_a.w;
            s_den[w-2][4] = den_b.x; s_den[w-2][5] = den_b.y;
            s_den[w-2][6] = den_b.z; s_den[w-2][7] = den_b.w;
        }
    }
    __syncthreads();
    if (w < 2) {
        #pragma unroll
        for (int h2 = 0; h2 < NHEADS; ++h2) {
            float4 v = ((const float4*)&s_buf[w][h2*HDIM])[lane];
            acc[h2].x += v.x; acc[h2].y += v.y; acc[h2].z += v.z; acc[h2].w += v.w;
        }
        den_a.x += s_den[w][0]; den_a.y += s_den[w][1];
        den_a.z += s_den[w][2]; den_a.w += s_den[w][3];
        den_b.x += s_den[w][4]; den_b.y += s_den[w][5];
        den_b.z += s_den[w][6]; den_b.w += s_den[w][7];
    }
    __syncthreads();
    if (w == 1) {
        #pragma unroll
        for (int h2 = 0; h2 < NHEADS; ++h2)
            ((float4*)&s_buf[0][h2*HDIM])[lane] = acc[h2];
        if (lane == 0) {
            s_den[0][0] = den_a.x; s_den[0][1] = den_a.y;
            s_den[0][2] = den_a.z; s_den[0][3] = den_a.w;
            s_den[0][4] = den_b.x; s_den[0][5] = den_b.y;
            s_den[0][6] = den_b.z; s_den[0][7] = den_b.w;
        }
    }
    __syncthreads();
    if (w == 0) {
        float* Sd = S_part + ((size_t)sl*NC + c) * (NHEADS*HDIM);
        #pragma unroll
        for (int h2 = 0; h2 < NHEADS; ++h2) {
            float4 v = ((const float4*)&s_buf[0][h2*HDIM])[lane];
            v.x += acc[h2].x; v.y += acc[h2].y; v.z += acc[h2].z; v.w += acc[h2].w;
            ((float4*)(Sd + h2*HDIM))[lane] = v;
        }
        if (lane == 0) {
            float* dp = den_part + ((size_t)sl*NC + c) * NHEADS;
            dp[0] = den_a.x + s_den[0][0]; dp[1] = den_a.y + s_den[0][1];
            dp[2] = den_a.z + s_den[0][2]; dp[3] = den_a.w + s_den[0][3];
            dp[4] = den_b.x + s_den[0][4]; dp[5] = den_b.y + s_den[0][5];
            dp[6] = den_b.z + s_den[0][6]; dp[7] = den_b.w + s_den[0][7];
        }
    }
}

// ---------------- stage 3: pooled -> po proj -> LN -> x ----------------
__global__ __launch_bounds__(256) void k_pool(const float* __restrict__ S_part,
        const float* __restrict__ den_part, const int* __restrict__ counts,
        const float* __restrict__ vw, const float* __restrict__ vb,
        const float* __restrict__ pow_, const float* __restrict__ pob,
        const float* __restrict__ png, const float* __restrict__ pnb,
        float* __restrict__ x) {
    int c = blockIdx.x, t = threadIdx.x;
    __shared__ float S_l[NHEADS*HDIM];  // 2048 floats
    __shared__ float pooled[HDIM];
    __shared__ float red[4];
    {
        float4 a0 = make_float4(0.f,0.f,0.f,0.f), a1 = a0;
        #pragma unroll
        for (int sl = 0; sl < SPLIT; ++sl) {
            const float4* sp = (const float4*)(S_part + ((size_t)sl*NC + c) * (NHEADS*HDIM));
            float4 v0 = sp[t], v1 = sp[t + 256];
            a0.x += v0.x; a0.y += v0.y; a0.z += v0.z; a0.w += v0.w;
            a1.x += v1.x; a1.y += v1.y; a1.z += v1.z; a1.w += v1.w;
        }
        ((float4*)S_l)[t] = a0;
        ((float4*)S_l)[t + 256] = a1;
    }
    int h = t >> 5;
    float dh = 0.f;
    #pragma unroll
    for (int sl = 0; sl < SPLIT; ++sl) dh += den_part[(sl*NC + c)*NHEADS + h];
    __syncthreads();
    float dx = dh > 0.f ? dh : 1.f;
    float s = vb[t] * dh;
    const float4* wr = (const float4*)(vw + (size_t)t * HDIM);
    const float4* sr = (const float4*)(S_l + h * HDIM);
    #pragma unroll 8
    for (int j = 0; j < HDIM/4; ++j) s += dot4(wr[j], sr[j]);
    pooled[t] = s / dx;
    __syncthreads();
    float o = pob[t];
    const float4* pr = (const float4*)(pow_ + (size_t)t * HDIM);
    const float4* pv = (const float4*)pooled;
    #pragma unroll 8
    for (int j = 0; j < HDIM/4; ++j) o += dot4(pr[j], pv[j]);
    float mu  = blk_sum256(o, red, t) * (1.f/256.f);
    float d   = o - mu;
    float var = blk_sum256(d*d, red, t) * (1.f/256.f);
    float y = d * rsqrtf(var + 1e-5f) * png[t] + pnb[t];
    x[c*HDIM + t] = (counts[c] > 0) ? y : 0.f;
}

// ---------------- generic small matmul: out[r][p] = in[r,:] . W[p,:] + b (opt gelu) ----------------
__global__ __launch_bounds__(256) void k_mm(const float* __restrict__ in,
        const float* __restrict__ W, const float* __restrict__ bias,
        float* __restrict__ out, int K, int P, int do_gelu) {
    int r = blockIdx.x;
    int p = blockIdx.y * 256 + threadIdx.x;
    __shared__ float xr[1024];
    for (int idx = threadIdx.x; idx < K; idx += 256) xr[idx] = in[(size_t)r*K + idx];
    __syncthreads();
    float s = bias[p];
    const float4* wr = (const float4*)(W + (size_t)p * K);
    const float4* xv = (const float4*)xr;
    for (int j = 0; j < (K >> 2); ++j) s += dot4(wr[j], xv[j]);
    if (do_gelu) s = gelu_exact(s);
    out[(size_t)r*P + p] = s;
}

// ---------------- matmul + residual + layernorm (writes x in place) ----------------
__global__ __launch_bounds__(256) void k_mm_res_ln(const float* __restrict__ in,
        const float* __restrict__ W, const float* __restrict__ bias,
        const float* __restrict__ g, const float* __restrict__ be,
        float* __restrict__ x, int K) {
    int r = blockIdx.x, t = threadIdx.x;
    __shared__ float xr[1024];
    __shared__ float red[4];
    for (int idx = t; idx < K; idx += 256) xr[idx] = in[(size_t)r*K + idx];
    __syncthreads();
    float s = bias[t];
    const float4* wr = (const float4*)(W + (size_t)t * K);
    const float4* xv = (const float4*)xr;
    for (int j = 0; j < (K >> 2); ++j) s += dot4(wr[j], xv[j]);
    float v = x[r*HDIM + t] + s;
    float mu  = blk_sum256(v, red, t) * (1.f/256.f);
    float d   = v - mu;
    float var = blk_sum256(d*d, red, t) * (1.f/256.f);
    x[r*HDIM + t] = d * rsqrtf(var + 1e-5f) * g[t] + be[t];
}

// ---------------- per-head attention over C=100, row-split 4x ----------------
// grid (NHEADS, 4): block handles rows [ns*25, ns*25+25) for head h.
// K,V,Q staged in LDS at stride KVPAD=36 floats (16B-aligned, spreads the
// stride-128B b128 reads across bank-quads); softmax in 8-lane groups; AV
// entirely from LDS (was ~100 scattered 4B global reads per output).
__global__ __launch_bounds__(256) void k_attn(const float* __restrict__ qkv,
        float* __restrict__ attn_out) {
    int h = blockIdx.x, ns = blockIdx.y, t = threadIdx.x;
    int n0 = ns * 25;
    __shared__ float k_l[NC * KVPAD];     // 14.4 KB
    __shared__ float v_l[NC * KVPAD];     // 14.4 KB
    __shared__ float q_l[25 * KVPAD];     // 3.6 KB
    __shared__ float sc[25 * NC];         // 10 KB
    for (int idx = t; idx < NC*HEADD; idx += 256) {
        int n = idx >> 5, d = idx & 31;
        k_l[n*KVPAD + d] = qkv[n*768 + 256 + h*HEADD + d];
        v_l[n*KVPAD + d] = qkv[n*768 + 512 + h*HEADD + d];
    }
    for (int idx = t; idx < 25*HEADD; idx += 256) {
        int n = idx >> 5, d = idx & 31;
        q_l[n*KVPAD + d] = qkv[(n0 + n)*768 + h*HEADD + d];
    }
    __syncthreads();
    const float scale = 0.17677669529663688f;
    for (int idx = t; idx < 25*NC; idx += 256) {
        int n = idx / NC, m = idx - n*NC;
        const float4* q4 = (const float4*)(q_l + n*KVPAD);
        const float4* k4 = (const float4*)(k_l + m*KVPAD);
        float s = 0.f;
        #pragma unroll
        for (int j = 0; j < HEADD/4; ++j) s += dot4(q4[j], k4[j]);
        sc[idx] = s * scale;
    }
    __syncthreads();
    {   // softmax: one 8-lane group per row
        int g = t >> 3, gl = t & 7;
        if (g < 25) {
            float mx = -1e30f;
            for (int m = gl; m < NC; m += 8) mx = fmaxf(mx, sc[g*NC + m]);
            #pragma unroll
            for (int o = 4; o >= 1; o >>= 1) mx = fmaxf(mx, __shfl_xor(mx, o, 8));
            float sum = 0.f;
            for (int m = gl; m < NC; m += 8) {
                float e = expf(sc[g*NC + m] - mx);
                sc[g*NC + m] = e; sum += e;
            }
            #pragma unroll
            for (int o = 4; o >= 1; o >>= 1) sum += __shfl_xor(sum, o, 8);
            float inv = 1.f / sum;
            for (int m = gl; m < NC; m += 8) sc[g*NC + m] *= inv;
        }
    }
    __syncthreads();
    for (int idx = t; idx < 25*HEADD; idx += 256) {
        int n = idx >> 5, d = idx & 31;
        float o = 0.f;
        #pragma unroll 4
        for (int m = 0; m < NC; ++m) o += sc[n*NC + m] * v_l[m*KVPAD + d];
        attn_out[(n0 + n)*HDIM + h*HEADD + d] = o;
    }
}

// ---------------- ranking head ----------------
__global__ __launch_bounds__(128) void k_head(const float* __restrict__ x,
        const float* __restrict__ r1w, const float* __restrict__ r1b,
        const float* __restrict__ r2w, const float* __restrict__ r2b,
        float* __restrict__ out) {
    int r = blockIdx.x, t = threadIdx.x;
    __shared__ float xr[HDIM];
    __shared__ float red[2];
    xr[t] = x[r*HDIM + t];
    xr[t + 128] = x[r*HDIM + t + 128];
    __syncthreads();
    float s = r1b[t];
    const float4* wr = (const float4*)(r1w + (size_t)t * HDIM);
    const float4* xv = (const float4*)xr;
    #pragma unroll 8
    for (int j = 0; j < HDIM/4; ++j) s += dot4(wr[j], xv[j]);
    s = gelu_exact(s);
    float contrib = s * r2w[t];
    #pragma unroll
    for (int m = 32; m >= 1; m >>= 1) contrib += __shfl_xor(contrib, m, 64);
    if ((t & 63) == 0) red[t >> 6] = contrib;
    __syncthreads();
    if (t == 0) out[r] = red[0] + red[1] + r2b[0];
}

extern "C" void kernel_launch(void* const* d_in, const int* in_sizes, int n_in,
                              void* d_out, int out_size, void* d_ws, size_t ws_size,
                              hipStream_t stream) {
    const float* emb   = (const float*)d_in[0];
    const int*   cidx  = (const int*)d_in[1];
    const float* q     = (const float*)d_in[3];
    const float* kw    = (const float*)d_in[4];
    const float* kb    = (const float*)d_in[5];
    const float* vw    = (const float*)d_in[6];
    const float* vb    = (const float*)d_in[7];
    const float* pow_  = (const float*)d_in[8];
    const float* pob   = (const float*)d_in[9];
    const float* png   = (const float*)d_in[10];
    const float* pnb   = (const float*)d_in[11];
    const float* tinw  = (const float*)d_in[12];
    const float* tinb  = (const float*)d_in[13];
    const float* toutw = (const float*)d_in[14];
    const float* toutb = (const float*)d_in[15];
    const float* ln1g  = (const float*)d_in[16];
    const float* ln1b  = (const float*)d_in[17];
    const float* ff1w  = (const float*)d_in[18];
    const float* ff1b  = (const float*)d_in[19];
    const float* ff2w  = (const float*)d_in[20];
    const float* ff2b  = (const float*)d_in[21];
    const float* ln2g  = (const float*)d_in[22];
    const float* ln2b  = (const float*)d_in[23];
    const float* r1w   = (const float*)d_in[24];
    const float* r1b   = (const float*)d_in[25];
    const float* r2w   = (const float*)d_in[26];
    const float* r2b   = (const float*)d_in[27];
    float* out = (float*)d_out;

    // --- workspace bump allocator (256B aligned) ---
    char* ws = (char*)d_ws;
    size_t off = 0;
    auto alloc = [&](size_t bytes) -> char* {
        off = (off + 255) & ~(size_t)255;
        char* p = ws + off;
        off += bytes;
        return p;
    };
    int*   hist   = (int*)alloc((size_t)NBLK * NC * 4);                          // 0.41 MB
    int*   bbase  = (int*)alloc((size_t)NBLK * NC * 4);                          // 0.41 MB
    int*   counts = (int*)alloc(NC * 4);
    int*   offs   = (int*)alloc((NC + 1) * 4);
    float* den_p  = (float*)alloc((size_t)SPLIT * NC * NHEADS * 4);
    float* S_part = (float*)alloc((size_t)SPLIT * NC * NHEADS * HDIM * 4);       // 8.2 MB
    float* qk_w   = (float*)alloc(NHEADS * HDIM * 4);
    float* qk_b   = (float*)alloc(NHEADS * 4);
    int*   nlist  = (int*)alloc((size_t)NNODES * 4);                             // 1 MB
    float* x      = (float*)alloc(NC * HDIM * 4);
    float* qkv    = (float*)alloc(NC * 3 * HDIM * 4);
    float* attn_o = (float*)alloc(NC * HDIM * 4);
    float* ffb    = (float*)alloc(NC * 4 * HDIM * 4);
    (void)ws_size; (void)in_sizes; (void)n_in; (void)out_size;

    k_qkw<<<NHEADS, HDIM, 0, stream>>>(q, kw, kb, qk_w, qk_b);
    k_hist<<<NBLK, 256, 0, stream>>>(cidx, hist);
    k_blockscan<<<NC, 256, 0, stream>>>(hist, bbase, counts);
    k_scan<<<1, 128, 0, stream>>>(counts, offs);
    k_scatter<<<NBLK, 256, 0, stream>>>(cidx, offs, bbase, nlist);
    k_accum<<<NC*SPLIT, 256, 0, stream>>>(emb, nlist, offs, counts, qk_w, qk_b, S_part, den_p);
    k_pool<<<NC, 256, 0, stream>>>(S_part, den_p, counts, vw, vb, pow_, pob, png, pnb, x);

    for (int l = 0; l < NLAYER; ++l) {
        k_mm<<<dim3(NC, 3), 256, 0, stream>>>(x, tinw + (size_t)l*3*HDIM*HDIM,
                                              tinb + (size_t)l*3*HDIM, qkv, HDIM, 3*HDIM, 0);
        k_attn<<<dim3(NHEADS, 4), 256, 0, stream>>>(qkv, attn_o);
        k_mm_res_ln<<<NC, 256, 0, stream>>>(attn_o, toutw + (size_t)l*HDIM*HDIM,
                                            toutb + (size_t)l*HDIM, ln1g + (size_t)l*HDIM,
                                            ln1b + (size_t)l*HDIM, x, HDIM);
        k_mm<<<dim3(NC, 4), 256, 0, stream>>>(x, ff1w + (size_t)l*4*HDIM*HDIM,
                                              ff1b + (size_t)l*4*HDIM, ffb, HDIM, 4*HDIM, 1);
        k_mm_res_ln<<<NC, 256, 0, stream>>>(ffb, ff2w + (size_t)l*HDIM*4*HDIM,
                                            ff2b + (size_t)l*HDIM, ln2g + (size_t)l*HDIM,
                                            ln2b + (size_t)l*HDIM, x, 4*HDIM);
    }
    k_head<<<NC, 128, 0, stream>>>(x, r1w, r1b, r2w, r2b, out);
}